// Round 4
// baseline (742.607 us; speedup 1.0000x reference)
//
#include <hip/hip_runtime.h>

// Sepconv: out[b,c,h,w] = sum_i vert[b,i,h,w] * sum_j inp[b,c,h+i,w+j]*horiz[b,j,h,w]
// Shapes: inp (2,3,530,882) f32; vert/horiz (2,51,480,832) f32; out (2,3,480,832) f32.

constexpr int B_ = 2, C_ = 3, F_ = 51, OH_ = 480, OW_ = 832;
constexpr int IH_ = OH_ + F_ - 1;  // 530
constexpr int IW_ = OW_ + F_ - 1;  // 882
constexpr int TW = 64;             // output tile width
constexpr int TH = 8;              // output tile height
constexpr int TCOLS = TW + F_ - 1; // 114 (input tile cols)
constexpr int TROWS = TH + F_ - 1; // 58  (input tile rows)
constexpr int NF2ROW = TCOLS / 2;  // 57 float2 per staged row
constexpr int NTHREADS = 256;      // 32 x-threads (2 outputs each) * 8 y-threads

// row2[k] holds input cols [2tx+2k, 2tx+2k+1]; ROW(t) = input col 2tx+t (t compile-time)
#define ROW(t) (((t) & 1) ? row2[(t) >> 1].y : row2[(t) >> 1].x)

__global__ __launch_bounds__(NTHREADS, 2)
void sepconv_kernel(const float* __restrict__ inp,
                    const float* __restrict__ vert,
                    const float* __restrict__ horiz,
                    float* __restrict__ out) {
  // 3 channels * 58 rows * 114 cols * 4B = 79,344 B -> 2 blocks/CU in 160 KB
  __shared__ float lds[C_ * TROWS * TCOLS];

  const int tid = threadIdx.x;
  const int tx = tid & 31;   // 0..31 -> output cols w0+2tx, w0+2tx+1
  const int ty = tid >> 5;   // 0..7  -> output row h0+ty
  const int w0 = blockIdx.x * TW;
  const int h0 = blockIdx.y * TH;
  const int b = blockIdx.z;

  // ---- stage input tile (all 3 channels) into LDS as float2 ----
  // All addresses in-bounds by construction: h0+57 <= 529, w0+113 <= 881.
  constexpr int TOTF2 = C_ * TROWS * NF2ROW;  // 9918
  #pragma unroll 1
  for (int idx = tid; idx < TOTF2; idx += NTHREADS) {
    const int c = idx / (TROWS * NF2ROW);
    const int rem = idx - c * (TROWS * NF2ROW);
    const int r = rem / NF2ROW;
    const int x2 = rem - r * NF2ROW;
    const float2 v = *reinterpret_cast<const float2*>(
        inp + ((b * C_ + c) * IH_ + h0 + r) * IW_ + w0 + 2 * x2);
    *reinterpret_cast<float2*>(lds + (c * TROWS + r) * TCOLS + 2 * x2) = v;
  }

  const int h = h0 + ty;
  const int w = w0 + 2 * tx;

  // ---- preload this thread's horizontal filters (read exactly once) ----
  // 51 x float2 = 102 VGPRs, live across whole kernel.
  float2 hz[F_];
  #pragma unroll
  for (int j = 0; j < F_; ++j)
    hz[j] = *reinterpret_cast<const float2*>(
        horiz + ((b * F_ + j) * OH_ + h) * OW_ + w);

  __syncthreads();

  float2 acc[C_] = {};

  #pragma unroll 1
  for (int i = 0; i < F_; ++i) {
    // vertical filter tap for this (i, pixel pair): read exactly once
    const float2 vt = *reinterpret_cast<const float2*>(
        vert + ((b * F_ + i) * OH_ + h) * OW_ + w);
    #pragma unroll
    for (int c = 0; c < C_; ++c) {
      const float2* rowp = reinterpret_cast<const float2*>(
          lds + (c * TROWS + ty + i) * TCOLS + 2 * tx);
      float2 row2[26];  // input cols 2tx .. 2tx+51
      #pragma unroll
      for (int k = 0; k < 26; ++k) row2[k] = rowp[k];  // 26x ds_read_b64
      // 4 independent FMA chains to saturate issue rate
      float hs0a = 0.f, hs0b = 0.f, hs1a = 0.f, hs1b = 0.f;
      #pragma unroll
      for (int j = 0; j < F_ - 1; j += 2) {
        hs0a += ROW(j)     * hz[j].x;
        hs1a += ROW(j + 1) * hz[j].y;
        hs0b += ROW(j + 1) * hz[j + 1].x;
        hs1b += ROW(j + 2) * hz[j + 1].y;
      }
      hs0a += ROW(50) * hz[50].x;  // tail tap j=50
      hs1a += ROW(51) * hz[50].y;
      const float hs0 = hs0a + hs0b;
      const float hs1 = hs1a + hs1b;
      acc[c].x += hs0 * vt.x;
      acc[c].y += hs1 * vt.y;
    }
  }

  #pragma unroll
  for (int c = 0; c < C_; ++c)
    *reinterpret_cast<float2*>(
        out + ((b * C_ + c) * OH_ + h) * OW_ + w) = acc[c];
}

extern "C" void kernel_launch(void* const* d_in, const int* in_sizes, int n_in,
                              void* d_out, int out_size, void* d_ws, size_t ws_size,
                              hipStream_t stream) {
  const float* inp   = (const float*)d_in[0];
  const float* vert  = (const float*)d_in[1];
  const float* horiz = (const float*)d_in[2];
  float* out = (float*)d_out;
  dim3 grid(OW_ / TW, OH_ / TH, B_);  // (13, 60, 2)
  sepconv_kernel<<<grid, NTHREADS, 0, stream>>>(inp, vert, horiz, out);
}

// Round 5
// 465.505 us; speedup vs baseline: 1.5953x; 1.5953x over previous
//
#include <hip/hip_runtime.h>

// Sepconv: out[b,c,h,w] = sum_i vert[b,i,h,w] * sum_j inp[b,c,h+i,w+j]*horiz[b,j,h,w]
// inp (2,3,530,882) f32; vert/horiz (2,51,480,832) f32; out (2,3,480,832) f32.
//
// v3: fp16 LDS staging + v_dot2_f32_f16.
//  - LDS tile stored as half2 (one uint per col-pair): 39,672 B -> 4 blocks/CU.
//  - Window reads: 26x ds_read_b32 per (i,c), lane stride 4B -> conflict-free.
//  - Horizontal filters packed per-pixel into half2 tap-pairs (52 VGPRs).
//  - f32 accumulation via v_dot2_f32_f16 (VOP3P), vert tap applied in f32.

constexpr int B_ = 2, C_ = 3, F_ = 51, OH_ = 480, OW_ = 832;
constexpr int IH_ = OH_ + F_ - 1;  // 530
constexpr int IW_ = OW_ + F_ - 1;  // 882
constexpr int TW = 64;             // output tile width (32 threads x 2 px)
constexpr int TH = 8;              // output tile height
constexpr int TCOLS2 = (TW + F_ - 1 + 1) / 2;  // 57 half2 per staged row (114 cols)
constexpr int TROWS = TH + F_ - 1; // 58 input rows
constexpr int NTHREADS = 256;
constexpr int JSTRIDE = OH_ * OW_; // 399360 floats between filter taps

typedef _Float16 half2_t __attribute__((ext_vector_type(2)));

static __device__ inline float fdot2(half2_t a, half2_t b, float c) {
#if __has_builtin(__builtin_amdgcn_fdot2)
  return __builtin_amdgcn_fdot2(a, b, c, false);
#else
  float d;
  asm("v_dot2_f32_f16 %0, %1, %2, %3" : "=v"(d) : "v"(a), "v"(b), "v"(c));
  return d;
#endif
}

static __device__ inline unsigned pk16(float x, float y) {
  return __builtin_bit_cast(unsigned, __builtin_amdgcn_cvt_pkrtz(x, y));
}
static __device__ inline half2_t as_h2(unsigned u) {
  return __builtin_bit_cast(half2_t, u);
}

__global__ __launch_bounds__(NTHREADS, 4)
void sepconv_kernel(const float* __restrict__ inp,
                    const float* __restrict__ vert,
                    const float* __restrict__ horiz,
                    float* __restrict__ out) {
  // 3 ch * 58 rows * 57 half2 = 9918 uints = 39,672 B -> 4 blocks/CU (158.7/160 KB)
  __shared__ unsigned lds_u[C_ * TROWS * TCOLS2];

  const int tid = threadIdx.x;
  const int tx = tid & 31;   // output cols w0+2tx, w0+2tx+1
  const int ty = tid >> 5;   // output row h0+ty
  const int w0 = blockIdx.x * TW;
  const int h0 = blockIdx.y * TH;
  const int b = blockIdx.z;

  // ---- stage input tile as half2 (f32 load -> cvt_pkrtz -> b32 write) ----
  constexpr int TOTU = C_ * TROWS * TCOLS2;  // 9918
  #pragma unroll 1
  for (int idx = tid; idx < TOTU; idx += NTHREADS) {
    const int c = idx / (TROWS * TCOLS2);
    const int rem = idx - c * (TROWS * TCOLS2);
    const int r = rem / TCOLS2;
    const int x2 = rem - r * TCOLS2;
    const float2 v = *reinterpret_cast<const float2*>(
        inp + ((b * C_ + c) * IH_ + h0 + r) * IW_ + w0 + 2 * x2);
    lds_u[idx] = pk16(v.x, v.y);  // stride-1 uints across threads: conflict-free
  }

  const int h = h0 + ty;
  const int w = w0 + 2 * tx;

  // ---- pack this thread's horizontal filters into per-pixel tap-pairs ----
  // px0 taps j=0..50 -> hz0[k]=(h0[2k],h0[2k+1]) k<25, hz0[25]=(h0[50],0)
  // px1 taps j=0..50 shifted one col -> hz1[0]=(0,h1[0]), hz1[k]=(h1[2k-1],h1[2k])
  unsigned hz0[26], hz1[26];
  {
    const float* hb = horiz + ((b * F_) * OH_ + h) * OW_ + w;
    float prev_x = 0.f, prev_y = 0.f;
    #pragma unroll
    for (int j = 0; j < F_; ++j) {
      const float2 g = *reinterpret_cast<const float2*>(hb + j * JSTRIDE);
      if ((j & 1) == 0) {
        const int k = j >> 1;
        hz1[k] = (j == 0) ? pk16(0.f, g.y) : pk16(prev_y, g.y);
        prev_x = g.x;
      } else {
        const int k = j >> 1;
        hz0[k] = pk16(prev_x, g.x);
        prev_y = g.y;
      }
    }
    hz0[25] = pk16(prev_x, 0.f);  // prev_x = h0[50] after j=50
  }

  __syncthreads();

  float2 acc[C_] = {};
  const float* vb = vert + ((b * F_) * OH_ + h) * OW_ + w;

  #pragma unroll 1
  for (int i = 0; i < F_; ++i) {
    const float2 vt = *reinterpret_cast<const float2*>(vb + i * JSTRIDE);
    #pragma unroll
    for (int c = 0; c < C_; ++c) {
      const unsigned* p = lds_u + (c * TROWS + ty + i) * TCOLS2 + tx;
      unsigned win[26];
      #pragma unroll
      for (int k = 0; k < 26; ++k) win[k] = p[k];  // ds_read_b32, banks distinct
      float s0a = 0.f, s0b = 0.f, s1a = 0.f, s1b = 0.f;
      #pragma unroll
      for (int k = 0; k < 26; k += 2) {
        s0a = fdot2(as_h2(win[k]),     as_h2(hz0[k]),     s0a);
        s1a = fdot2(as_h2(win[k]),     as_h2(hz1[k]),     s1a);
        s0b = fdot2(as_h2(win[k + 1]), as_h2(hz0[k + 1]), s0b);
        s1b = fdot2(as_h2(win[k + 1]), as_h2(hz1[k + 1]), s1b);
      }
      acc[c].x += (s0a + s0b) * vt.x;
      acc[c].y += (s1a + s1b) * vt.y;
    }
  }

  #pragma unroll
  for (int c = 0; c < C_; ++c)
    *reinterpret_cast<float2*>(
        out + ((b * C_ + c) * OH_ + h) * OW_ + w) = acc[c];
}

extern "C" void kernel_launch(void* const* d_in, const int* in_sizes, int n_in,
                              void* d_out, int out_size, void* d_ws, size_t ws_size,
                              hipStream_t stream) {
  const float* inp   = (const float*)d_in[0];
  const float* vert  = (const float*)d_in[1];
  const float* horiz = (const float*)d_in[2];
  float* out = (float*)d_out;
  dim3 grid(OW_ / TW, OH_ / TH, B_);  // (13, 60, 2)
  sepconv_kernel<<<grid, NTHREADS, 0, stream>>>(inp, vert, horiz, out);
}